// Round 1
// baseline (216.451 us; speedup 1.0000x reference)
//
#include <hip/hip_runtime.h>

// Problem constants
#define B 8
#define S 4096
#define H 32
#define D 128
#define DM 4096   // H*D

#define NT 1024
#define WAVES 16  // NT/64

// ---------------------------------------------------------------------------
// Kernel 1: q = hidden @ Wq^T + bq     (hidden [B,DM], Wq [DM,DM] row-major)
// One wave computes 2 output columns (j0,j1) for all 8 batches.
// Wq rows are read exactly once, coalesced float4. hidden is L2-resident.
// ---------------------------------------------------------------------------
__global__ __launch_bounds__(256) void qproj_kernel(
    const float* __restrict__ hidden, const float* __restrict__ Wq,
    const float* __restrict__ bq, float* __restrict__ qout)
{
    const int lane = threadIdx.x & 63;
    const int wave = threadIdx.x >> 6;
    const int j0 = (blockIdx.x * 4 + wave) * 2;
    const int j1 = j0 + 1;

    const float4* __restrict__ w0 = (const float4*)(Wq + (size_t)j0 * DM);
    const float4* __restrict__ w1 = (const float4*)(Wq + (size_t)j1 * DM);
    const float4* __restrict__ hid = (const float4*)hidden;

    float a0[B], a1[B];
#pragma unroll
    for (int b = 0; b < B; ++b) { a0[b] = 0.f; a1[b] = 0.f; }

#pragma unroll
    for (int i = 0; i < DM / (4 * 64); ++i) {   // 16 iterations
        const int idx = lane + 64 * i;
        const float4 wv0 = w0[idx];
        const float4 wv1 = w1[idx];
#pragma unroll
        for (int b = 0; b < B; ++b) {
            const float4 hv = hid[b * (DM / 4) + idx];
            a0[b] += wv0.x * hv.x + wv0.y * hv.y + wv0.z * hv.z + wv0.w * hv.w;
            a1[b] += wv1.x * hv.x + wv1.y * hv.y + wv1.z * hv.z + wv1.w * hv.w;
        }
    }
    // butterfly wave reductions (all lanes end with the total)
#pragma unroll
    for (int b = 0; b < B; ++b) {
#pragma unroll
        for (int mk = 1; mk <= 32; mk <<= 1) {
            a0[b] += __shfl_xor(a0[b], mk);
            a1[b] += __shfl_xor(a1[b], mk);
        }
    }
    if (lane == 0) {
        const float bias0 = bq[j0];
        const float bias1 = bq[j1];
#pragma unroll
        for (int b = 0; b < B; ++b) {
            qout[b * DM + j0] = a0[b] + bias0;
            qout[b * DM + j1] = a1[b] + bias1;
        }
    }
}

// ---------------------------------------------------------------------------
// Kernel 2: attention decode. One block per (b,h). 1024 threads = 16 waves.
// Phase 1: scores[s] = q . K[b,s,h,:]   (2 s per wave per iter, 32-lane groups)
// Softmax in LDS (keep unnormalized exp, scale output by 1/sum).
// Phase 2: out[d] = sum_s p[s] * V[b,s,h,d]
// ---------------------------------------------------------------------------
__global__ __launch_bounds__(NT) void attn_kernel(
    const float* __restrict__ kptr, const float* __restrict__ vptr,
    const float* __restrict__ qws, float* __restrict__ out)
{
    __shared__ float sc[S];             // 16 KB
    __shared__ float red[WAVES];
    __shared__ float outp[WAVES][D];    // 8 KB

    const int tid  = threadIdx.x;
    const int lane = tid & 63;
    const int wave = tid >> 6;
    const int g    = lane >> 5;         // 32-lane group: 0/1
    const int l    = lane & 31;
    const int b    = blockIdx.x >> 5;   // H = 32
    const int h    = blockIdx.x & (H - 1);

    const size_t base = ((size_t)b * S * H + h) * D;  // element offset of (b, s=0, h, d=0)
    const float* kb = kptr + base;
    const float* vb = vptr + base;

    // q fragment: lanes of each 32-group hold the full 128-d q as float4 slices
    const float4 q4 = *(const float4*)(qws + (size_t)b * DM + h * D + 4 * l);

    // ---- Phase 1: scores ----
#pragma unroll 2
    for (int it = 0; it < S / 32; ++it) {           // 128 iterations
        const int s = it * 32 + 2 * wave + g;
        const float4 k4 = *(const float4*)(kb + (size_t)s * DM + 4 * l);
        float p = q4.x * k4.x + q4.y * k4.y + q4.z * k4.z + q4.w * k4.w;
        p += __shfl_xor(p, 16);
        p += __shfl_xor(p, 8);
        p += __shfl_xor(p, 4);
        p += __shfl_xor(p, 2);
        p += __shfl_xor(p, 1);
        if (l == 0) sc[s] = p;
    }
    __syncthreads();

    // ---- Softmax: block max ----
    float m = -3.4e38f;
    for (int i = tid; i < S; i += NT) m = fmaxf(m, sc[i]);
#pragma unroll
    for (int mk = 1; mk <= 32; mk <<= 1) m = fmaxf(m, __shfl_xor(m, mk));
    if (lane == 0) red[wave] = m;
    __syncthreads();
    float M = red[0];
#pragma unroll
    for (int w = 1; w < WAVES; ++w) M = fmaxf(M, red[w]);

    // ---- exp + block sum (keep unnormalized exp in sc) ----
    float lsum = 0.f;
    for (int i = tid; i < S; i += NT) {
        const float e = __expf(sc[i] - M);
        sc[i] = e;
        lsum += e;
    }
#pragma unroll
    for (int mk = 1; mk <= 32; mk <<= 1) lsum += __shfl_xor(lsum, mk);
    __syncthreads();                    // red reads done; sc writes visible
    if (lane == 0) red[wave] = lsum;
    __syncthreads();
    float tot = 0.f;
#pragma unroll
    for (int w = 0; w < WAVES; ++w) tot += red[w];
    const float inv = 1.0f / tot;

    // ---- Phase 2: out = P @ V ----
    float4 acc = make_float4(0.f, 0.f, 0.f, 0.f);
    const int s0 = wave * (S / WAVES);  // 256 contiguous s per wave
#pragma unroll 2
    for (int i = 0; i < S / WAVES; i += 2) {
        const int s = s0 + i + g;
        const float p = sc[s];          // LDS broadcast within each 32-group
        const float4 v4 = *(const float4*)(vb + (size_t)s * DM + 4 * l);
        acc.x += p * v4.x;
        acc.y += p * v4.y;
        acc.z += p * v4.z;
        acc.w += p * v4.w;
    }
    // combine the two 32-lane groups (same d-slice, disjoint s)
    acc.x += __shfl_xor(acc.x, 32);
    acc.y += __shfl_xor(acc.y, 32);
    acc.z += __shfl_xor(acc.z, 32);
    acc.w += __shfl_xor(acc.w, 32);
    if (g == 0) *(float4*)(&outp[wave][4 * l]) = acc;
    __syncthreads();

    // ---- final cross-wave reduce + write ----
    if (tid < D) {
        float r = 0.f;
#pragma unroll
        for (int w = 0; w < WAVES; ++w) r += outp[w][tid];
        out[(size_t)(b * H + h) * D + tid] = r * inv;
    }
}

extern "C" void kernel_launch(void* const* d_in, const int* in_sizes, int n_in,
                              void* d_out, int out_size, void* d_ws, size_t ws_size,
                              hipStream_t stream)
{
    const float* hidden = (const float*)d_in[0];
    const float* keys   = (const float*)d_in[1];
    const float* vals   = (const float*)d_in[2];
    const float* Wq     = (const float*)d_in[3];
    const float* bq     = (const float*)d_in[4];
    float* outp = (float*)d_out;
    float* qws  = (float*)d_ws;   // B*DM floats = 128 KB scratch for q

    qproj_kernel<<<DM / 8, 256, 0, stream>>>(hidden, Wq, bq, qws);
    attn_kernel<<<B * H, NT, 0, stream>>>(keys, vals, qws, outp);
}